// Round 1
// baseline (5350.400 us; speedup 1.0000x reference)
//
#include <hip/hip_runtime.h>
#include <cstdint>
#include <cstddef>

#define B_  4
#define T_  2048
#define D_  1024
#define H_  16
#define DK_ 64
// M = B*T = 8192, K = D = 1024, N = D = 1024 for the projection GEMMs

// ---------------------------------------------------------------------------
// QKV projection: out_sel[b,h,t,dk] = sum_c x[b,t,c] * w_sel[h,dk,c] + b_sel[h,dk]
// GEMM view: C[m][n] = sum_k A[m][k] * B[n][k], A = x (row-major M x K),
// B = w (row-major N x K since w is [H,DK,D] and n = h*64+dk).
// 64x64 output tile per 256-thread block, 4x4 micro-tile per thread, K-chunk 16.
// ---------------------------------------------------------------------------
__global__ __launch_bounds__(256) void qkv_gemm(
    const float* __restrict__ x,
    const float* __restrict__ wq, const float* __restrict__ bq,
    const float* __restrict__ wk, const float* __restrict__ bk,
    const float* __restrict__ wv, const float* __restrict__ bv,
    float* __restrict__ qkv_out)    // q,k,v contiguous: each B_*T_*D_ floats
{
    const int sel = blockIdx.z;
    const float* w    = (sel == 0) ? wq : (sel == 1) ? wk : wv;
    const float* bias = (sel == 0) ? bq : (sel == 1) ? bk : bv;
    float* out = qkv_out + (size_t)sel * ((size_t)B_ * T_ * D_);

    const int m0 = blockIdx.x * 64;     // row tile (over B*T)
    const int h  = blockIdx.y;          // head == n-tile (N tile width 64 == DK)
    const int tid = threadIdx.x;
    const int tx = tid & 15;            // n-direction
    const int ty = tid >> 4;            // m-direction

    __shared__ float As[16][68];        // [k][m], padded: row stride 272B (16B aligned)
    __shared__ float Bs[16][68];        // [k][n]

    float acc[4][4];
#pragma unroll
    for (int i = 0; i < 4; ++i)
#pragma unroll
        for (int j = 0; j < 4; ++j) acc[i][j] = 0.f;

    const int lr = tid >> 2;            // 0..63: tile row loaded by this thread
    const int lc = (tid & 3) * 4;       // 0,4,8,12: k-offset within chunk

    const float* aRow = x + (size_t)(m0 + lr) * D_;
    const float* bRow = w + (size_t)(h * 64 + lr) * D_;

    for (int c0 = 0; c0 < D_; c0 += 16) {
        float4 a4 = *(const float4*)(aRow + c0 + lc);
        float4 b4 = *(const float4*)(bRow + c0 + lc);
        __syncthreads();
        As[lc + 0][lr] = a4.x; As[lc + 1][lr] = a4.y;
        As[lc + 2][lr] = a4.z; As[lc + 3][lr] = a4.w;
        Bs[lc + 0][lr] = b4.x; Bs[lc + 1][lr] = b4.y;
        Bs[lc + 2][lr] = b4.z; Bs[lc + 3][lr] = b4.w;
        __syncthreads();
#pragma unroll
        for (int kk = 0; kk < 16; ++kk) {
            float4 av = *(const float4*)&As[kk][ty * 4];
            float4 bv4 = *(const float4*)&Bs[kk][tx * 4];
            float a[4] = {av.x, av.y, av.z, av.w};
            float b[4] = {bv4.x, bv4.y, bv4.z, bv4.w};
#pragma unroll
            for (int i = 0; i < 4; ++i)
#pragma unroll
                for (int j = 0; j < 4; ++j)
                    acc[i][j] += a[i] * b[j];
        }
    }

    const int dk0 = tx * 4;
    float4 b4 = *(const float4*)(bias + h * DK_ + dk0);
#pragma unroll
    for (int i = 0; i < 4; ++i) {
        const int m = m0 + ty * 4 + i;
        const int b = m >> 11;          // / T_
        const int t = m & (T_ - 1);
        float4 r;
        r.x = acc[i][0] + b4.x;
        r.y = acc[i][1] + b4.y;
        r.z = acc[i][2] + b4.z;
        r.w = acc[i][3] + b4.w;
        *(float4*)(out + ((size_t)((b * H_ + h) * T_ + t)) * DK_ + dk0) = r;
    }
}

// ---------------------------------------------------------------------------
// Flash-style causal attention, one thread per (b,h,t).
// q (pre-scaled by 1/sqrt(DK)) and the o accumulator live in registers (64 fl).
// All lanes sweep s from 0: at step s every active lane reads the same k/v row
// -> same-address float4 loads, L1 broadcast. Online softmax (m, l) updates.
// Output written in concat-head layout yh[b, t, h*64 + d].
// ---------------------------------------------------------------------------
__global__ __launch_bounds__(256) void attn(
    const float* __restrict__ q_, const float* __restrict__ k_,
    const float* __restrict__ v_, float* __restrict__ yh)
{
    const int idx = blockIdx.x * 256 + threadIdx.x;
    const int t  = idx & (T_ - 1);
    const int bh = idx >> 11;           // b*H + h
    const int h  = bh & (H_ - 1);
    const int b  = bh >> 4;

    const size_t base = (size_t)bh * T_ * DK_;
    const float* qr = q_ + base + (size_t)t * DK_;
    const float* kb = k_ + base;
    const float* vb = v_ + base;

    float4 q[16];
#pragma unroll
    for (int j = 0; j < 16; ++j) {
        float4 qv = *(const float4*)(qr + j * 4);
        qv.x *= 0.125f; qv.y *= 0.125f; qv.z *= 0.125f; qv.w *= 0.125f;
        q[j] = qv;
    }
    float4 o[16];
#pragma unroll
    for (int j = 0; j < 16; ++j) o[j] = make_float4(0.f, 0.f, 0.f, 0.f);

    float m = -1e30f;
    float l = 0.f;

    for (int s = 0; s <= t; ++s) {
        const float4* kr = (const float4*)(kb + (size_t)s * DK_);
        float dot = 0.f;
#pragma unroll
        for (int j = 0; j < 16; ++j) {
            float4 kv = kr[j];
            dot += q[j].x * kv.x + q[j].y * kv.y + q[j].z * kv.z + q[j].w * kv.w;
        }
        const float mn    = fmaxf(m, dot);
        const float alpha = __expf(m - mn);     // underflows to 0 on first iter
        const float p     = __expf(dot - mn);
        l = l * alpha + p;
        m = mn;
        const float4* vr = (const float4*)(vb + (size_t)s * DK_);
#pragma unroll
        for (int j = 0; j < 16; ++j) {
            float4 vv = vr[j];
            o[j].x = o[j].x * alpha + p * vv.x;
            o[j].y = o[j].y * alpha + p * vv.y;
            o[j].z = o[j].z * alpha + p * vv.z;
            o[j].w = o[j].w * alpha + p * vv.w;
        }
    }

    const float inv = 1.f / l;
    float* yrow = yh + ((size_t)(b * T_ + t)) * D_ + h * DK_;
#pragma unroll
    for (int j = 0; j < 16; ++j) {
        float4 r;
        r.x = o[j].x * inv; r.y = o[j].y * inv;
        r.z = o[j].z * inv; r.w = o[j].w * inv;
        *(float4*)(yrow + j * 4) = r;
    }
}

// ---------------------------------------------------------------------------
// Output projection: out[m][n] = sum_k yh[m][k] * wo[n][k] + bo[n]
// yh row-major [8192][1024], wo row-major [1024][1024]. Same tiling as above.
// ---------------------------------------------------------------------------
__global__ __launch_bounds__(256) void out_gemm(
    const float* __restrict__ yh, const float* __restrict__ wo,
    const float* __restrict__ bo, float* __restrict__ out)
{
    const int m0 = blockIdx.x * 64;
    const int n0 = blockIdx.y * 64;
    const int tid = threadIdx.x;
    const int tx = tid & 15;
    const int ty = tid >> 4;

    __shared__ float As[16][68];
    __shared__ float Bs[16][68];

    float acc[4][4];
#pragma unroll
    for (int i = 0; i < 4; ++i)
#pragma unroll
        for (int j = 0; j < 4; ++j) acc[i][j] = 0.f;

    const int lr = tid >> 2;
    const int lc = (tid & 3) * 4;

    const float* aRow = yh + (size_t)(m0 + lr) * D_;
    const float* bRow = wo + (size_t)(n0 + lr) * D_;

    for (int c0 = 0; c0 < D_; c0 += 16) {
        float4 a4 = *(const float4*)(aRow + c0 + lc);
        float4 b4 = *(const float4*)(bRow + c0 + lc);
        __syncthreads();
        As[lc + 0][lr] = a4.x; As[lc + 1][lr] = a4.y;
        As[lc + 2][lr] = a4.z; As[lc + 3][lr] = a4.w;
        Bs[lc + 0][lr] = b4.x; Bs[lc + 1][lr] = b4.y;
        Bs[lc + 2][lr] = b4.z; Bs[lc + 3][lr] = b4.w;
        __syncthreads();
#pragma unroll
        for (int kk = 0; kk < 16; ++kk) {
            float4 av = *(const float4*)&As[kk][ty * 4];
            float4 bv4 = *(const float4*)&Bs[kk][tx * 4];
            float a[4] = {av.x, av.y, av.z, av.w};
            float b[4] = {bv4.x, bv4.y, bv4.z, bv4.w};
#pragma unroll
            for (int i = 0; i < 4; ++i)
#pragma unroll
                for (int j = 0; j < 4; ++j)
                    acc[i][j] += a[i] * b[j];
        }
    }

    float4 b4 = *(const float4*)(bo + n0 + tx * 4);
#pragma unroll
    for (int i = 0; i < 4; ++i) {
        const int m = m0 + ty * 4 + i;
        float4 r;
        r.x = acc[i][0] + b4.x;
        r.y = acc[i][1] + b4.y;
        r.z = acc[i][2] + b4.z;
        r.w = acc[i][3] + b4.w;
        *(float4*)(out + (size_t)m * D_ + n0 + tx * 4) = r;
    }
}

// ---------------------------------------------------------------------------
extern "C" void kernel_launch(void* const* d_in, const int* in_sizes, int n_in,
                              void* d_out, int out_size, void* d_ws, size_t ws_size,
                              hipStream_t stream) {
    const float* x  = (const float*)d_in[0];
    const float* wq = (const float*)d_in[1];
    const float* bq = (const float*)d_in[2];
    const float* wk = (const float*)d_in[3];
    const float* bk = (const float*)d_in[4];
    const float* wv = (const float*)d_in[5];
    const float* bv = (const float*)d_in[6];
    const float* wo = (const float*)d_in[7];
    const float* bo = (const float*)d_in[8];
    float* out = (float*)d_out;

    const size_t BTD = (size_t)B_ * T_ * D_;      // 8.4M floats = 32 MB
    float* q  = (float*)d_ws;                     // [B,H,T,DK]
    float* k  = q + BTD;
    float* v  = k + BTD;
    float* yh = v + BTD;                          // [B,T,D] concat-head
    // total workspace use: 4 * 32 MB = 128 MB

    // 1. QKV projections
    dim3 g1((B_ * T_) / 64, H_, 3);
    qkv_gemm<<<g1, 256, 0, stream>>>(x, wq, bq, wk, bk, wv, bv, q);

    // 2. causal flash attention
    dim3 g2((B_ * H_ * T_) / 256);
    attn<<<g2, 256, 0, stream>>>(q, k, v, yh);

    // 3. output projection
    dim3 g3((B_ * T_) / 64, D_ / 64);
    out_gemm<<<g3, 256, 0, stream>>>(yh, wo, bo, out);
}

// Round 2
// 2997.606 us; speedup vs baseline: 1.7849x; 1.7849x over previous
//
#include <hip/hip_runtime.h>
#include <cstdint>
#include <cstddef>

#define B_  4
#define T_  2048
#define D_  1024
#define H_  16
#define DK_ 64
#define QROWS 256     // q-rows per block (one per thread)
#define STILE 64      // k/v rows staged in LDS per tile

// ---------------------------------------------------------------------------
// QKV projection: out_sel[b,h,t,dk] = sum_c x[b,t,c] * w_sel[h,dk,c] + b_sel[h,dk]
// 64x64 tile / block, 4x4 micro-tile / thread, K-chunk 16. (unchanged R1)
// ---------------------------------------------------------------------------
__global__ __launch_bounds__(256) void qkv_gemm(
    const float* __restrict__ x,
    const float* __restrict__ wq, const float* __restrict__ bq,
    const float* __restrict__ wk, const float* __restrict__ bk,
    const float* __restrict__ wv, const float* __restrict__ bv,
    float* __restrict__ qkv_out)
{
    const int sel = blockIdx.z;
    const float* w    = (sel == 0) ? wq : (sel == 1) ? wk : wv;
    const float* bias = (sel == 0) ? bq : (sel == 1) ? bk : bv;
    float* out = qkv_out + (size_t)sel * ((size_t)B_ * T_ * D_);

    const int m0 = blockIdx.x * 64;
    const int h  = blockIdx.y;
    const int tid = threadIdx.x;
    const int tx = tid & 15;
    const int ty = tid >> 4;

    __shared__ float As[16][68];
    __shared__ float Bs[16][68];

    float acc[4][4];
#pragma unroll
    for (int i = 0; i < 4; ++i)
#pragma unroll
        for (int j = 0; j < 4; ++j) acc[i][j] = 0.f;

    const int lr = tid >> 2;
    const int lc = (tid & 3) * 4;

    const float* aRow = x + (size_t)(m0 + lr) * D_;
    const float* bRow = w + (size_t)(h * 64 + lr) * D_;

    for (int c0 = 0; c0 < D_; c0 += 16) {
        float4 a4 = *(const float4*)(aRow + c0 + lc);
        float4 b4 = *(const float4*)(bRow + c0 + lc);
        __syncthreads();
        As[lc + 0][lr] = a4.x; As[lc + 1][lr] = a4.y;
        As[lc + 2][lr] = a4.z; As[lc + 3][lr] = a4.w;
        Bs[lc + 0][lr] = b4.x; Bs[lc + 1][lr] = b4.y;
        Bs[lc + 2][lr] = b4.z; Bs[lc + 3][lr] = b4.w;
        __syncthreads();
#pragma unroll
        for (int kk = 0; kk < 16; ++kk) {
            float4 av = *(const float4*)&As[kk][ty * 4];
            float4 bv4 = *(const float4*)&Bs[kk][tx * 4];
            float a[4] = {av.x, av.y, av.z, av.w};
            float b[4] = {bv4.x, bv4.y, bv4.z, bv4.w};
#pragma unroll
            for (int i = 0; i < 4; ++i)
#pragma unroll
                for (int j = 0; j < 4; ++j)
                    acc[i][j] += a[i] * b[j];
        }
    }

    const int dk0 = tx * 4;
    float4 b4 = *(const float4*)(bias + h * DK_ + dk0);
#pragma unroll
    for (int i = 0; i < 4; ++i) {
        const int m = m0 + ty * 4 + i;
        const int b = m >> 11;
        const int t = m & (T_ - 1);
        float4 r;
        r.x = acc[i][0] + b4.x;
        r.y = acc[i][1] + b4.y;
        r.z = acc[i][2] + b4.z;
        r.w = acc[i][3] + b4.w;
        *(float4*)(out + ((size_t)((b * H_ + h) * T_ + t)) * DK_ + dk0) = r;
    }
}

// ---------------------------------------------------------------------------
// Block-tiled causal flash attention.
// block = 256 threads = 256 consecutive q-rows of one (b,h). K/V staged in
// LDS 64 rows at a time; inner s-loop is block-uniform so every lane reads
// the SAME K/V row from LDS (broadcast, conflict-free). Online softmax in
// registers. Waves fully above the diagonal skip the inner loop (barriers
// remain uniform). Output in concat-head layout yh[b, t, h*64+d].
// ---------------------------------------------------------------------------
__global__ __launch_bounds__(256) void attn(
    const float* __restrict__ q_, const float* __restrict__ k_,
    const float* __restrict__ v_, float* __restrict__ yh)
{
    const int tq0 = blockIdx.x * QROWS;
    const int bh  = blockIdx.y;            // b*H + h
    const int h   = bh & (H_ - 1);
    const int b   = bh >> 4;
    const int tid = threadIdx.x;
    const int t   = tq0 + tid;             // this thread's q row

    const size_t base = (size_t)bh * T_ * DK_;
    const float* qr = q_ + base + (size_t)t * DK_;
    const float* kb = k_ + base;
    const float* vb = v_ + base;

    __shared__ float Ks[STILE][68];        // 64 rows, stride 68 (272B, 16B-aligned)
    __shared__ float Vs[STILE][68];

    float4 q[16];
#pragma unroll
    for (int j = 0; j < 16; ++j) {
        float4 qv = *(const float4*)(qr + j * 4);
        qv.x *= 0.125f; qv.y *= 0.125f; qv.z *= 0.125f; qv.w *= 0.125f;
        q[j] = qv;
    }
    float4 o[16];
#pragma unroll
    for (int j = 0; j < 16; ++j) o[j] = make_float4(0.f, 0.f, 0.f, 0.f);

    float m = -1e30f;
    float l = 0.f;

    const int lr = tid >> 2;               // staged row 0..63
    const int lc = (tid & 3) * 16;         // col chunk 0,16,32,48

    const int nTiles = (tq0 + QROWS) / STILE;   // covers s in [0, tq0+255]
    for (int tile = 0; tile < nTiles; ++tile) {
        const int s0 = tile * STILE;

        __syncthreads();                   // previous tile fully consumed
        {
            const float* krow = kb + (size_t)(s0 + lr) * DK_ + lc;
            const float* vrow = vb + (size_t)(s0 + lr) * DK_ + lc;
            float4 kk0 = ((const float4*)krow)[0];
            float4 kk1 = ((const float4*)krow)[1];
            float4 kk2 = ((const float4*)krow)[2];
            float4 kk3 = ((const float4*)krow)[3];
            float4 vv0 = ((const float4*)vrow)[0];
            float4 vv1 = ((const float4*)vrow)[1];
            float4 vv2 = ((const float4*)vrow)[2];
            float4 vv3 = ((const float4*)vrow)[3];
            *(float4*)&Ks[lr][lc +  0] = kk0;
            *(float4*)&Ks[lr][lc +  4] = kk1;
            *(float4*)&Ks[lr][lc +  8] = kk2;
            *(float4*)&Ks[lr][lc + 12] = kk3;
            *(float4*)&Vs[lr][lc +  0] = vv0;
            *(float4*)&Vs[lr][lc +  4] = vv1;
            *(float4*)&Vs[lr][lc +  8] = vv2;
            *(float4*)&Vs[lr][lc + 12] = vv3;
        }
        __syncthreads();

        if (s0 <= t) {                     // whole wave skips if fully masked
#pragma unroll 4
            for (int ss = 0; ss < STILE; ++ss) {
                const int s = s0 + ss;
                const float4* kr = (const float4*)&Ks[ss][0];
                float d0 = 0.f, d1 = 0.f, d2 = 0.f, d3 = 0.f;
#pragma unroll
                for (int j = 0; j < 16; j += 4) {
                    float4 ka = kr[j + 0];
                    float4 kbv = kr[j + 1];
                    float4 kc = kr[j + 2];
                    float4 kd = kr[j + 3];
                    d0 += q[j + 0].x * ka.x  + q[j + 0].y * ka.y
                        + q[j + 0].z * ka.z  + q[j + 0].w * ka.w;
                    d1 += q[j + 1].x * kbv.x + q[j + 1].y * kbv.y
                        + q[j + 1].z * kbv.z + q[j + 1].w * kbv.w;
                    d2 += q[j + 2].x * kc.x  + q[j + 2].y * kc.y
                        + q[j + 2].z * kc.z  + q[j + 2].w * kc.w;
                    d3 += q[j + 3].x * kd.x  + q[j + 3].y * kd.y
                        + q[j + 3].z * kd.z  + q[j + 3].w * kd.w;
                }
                float dot = (d0 + d1) + (d2 + d3);
                dot = (s <= t) ? dot : -1e30f;

                const float mn    = fmaxf(m, dot);
                const float alpha = __expf(m - mn);
                const float p     = __expf(dot - mn);
                l = l * alpha + p;
                m = mn;

                const float4* vr = (const float4*)&Vs[ss][0];
#pragma unroll
                for (int j = 0; j < 16; ++j) {
                    float4 vv = vr[j];
                    o[j].x = o[j].x * alpha + p * vv.x;
                    o[j].y = o[j].y * alpha + p * vv.y;
                    o[j].z = o[j].z * alpha + p * vv.z;
                    o[j].w = o[j].w * alpha + p * vv.w;
                }
            }
        }
    }

    const float inv = 1.f / l;
    float* yrow = yh + ((size_t)(b * T_ + t)) * D_ + h * DK_;
#pragma unroll
    for (int j = 0; j < 16; ++j) {
        float4 r;
        r.x = o[j].x * inv; r.y = o[j].y * inv;
        r.z = o[j].z * inv; r.w = o[j].w * inv;
        *(float4*)(yrow + j * 4) = r;
    }
}

// ---------------------------------------------------------------------------
// Output projection: out[m][n] = sum_k yh[m][k] * wo[n][k] + bo[n] (unchanged)
// ---------------------------------------------------------------------------
__global__ __launch_bounds__(256) void out_gemm(
    const float* __restrict__ yh, const float* __restrict__ wo,
    const float* __restrict__ bo, float* __restrict__ out)
{
    const int m0 = blockIdx.x * 64;
    const int n0 = blockIdx.y * 64;
    const int tid = threadIdx.x;
    const int tx = tid & 15;
    const int ty = tid >> 4;

    __shared__ float As[16][68];
    __shared__ float Bs[16][68];

    float acc[4][4];
#pragma unroll
    for (int i = 0; i < 4; ++i)
#pragma unroll
        for (int j = 0; j < 4; ++j) acc[i][j] = 0.f;

    const int lr = tid >> 2;
    const int lc = (tid & 3) * 4;

    const float* aRow = yh + (size_t)(m0 + lr) * D_;
    const float* bRow = wo + (size_t)(n0 + lr) * D_;

    for (int c0 = 0; c0 < D_; c0 += 16) {
        float4 a4 = *(const float4*)(aRow + c0 + lc);
        float4 b4 = *(const float4*)(bRow + c0 + lc);
        __syncthreads();
        As[lc + 0][lr] = a4.x; As[lc + 1][lr] = a4.y;
        As[lc + 2][lr] = a4.z; As[lc + 3][lr] = a4.w;
        Bs[lc + 0][lr] = b4.x; Bs[lc + 1][lr] = b4.y;
        Bs[lc + 2][lr] = b4.z; Bs[lc + 3][lr] = b4.w;
        __syncthreads();
#pragma unroll
        for (int kk = 0; kk < 16; ++kk) {
            float4 av = *(const float4*)&As[kk][ty * 4];
            float4 bv4 = *(const float4*)&Bs[kk][tx * 4];
            float a[4] = {av.x, av.y, av.z, av.w};
            float b[4] = {bv4.x, bv4.y, bv4.z, bv4.w};
#pragma unroll
            for (int i = 0; i < 4; ++i)
#pragma unroll
                for (int j = 0; j < 4; ++j)
                    acc[i][j] += a[i] * b[j];
        }
    }

    float4 b4 = *(const float4*)(bo + n0 + tx * 4);
#pragma unroll
    for (int i = 0; i < 4; ++i) {
        const int m = m0 + ty * 4 + i;
        float4 r;
        r.x = acc[i][0] + b4.x;
        r.y = acc[i][1] + b4.y;
        r.z = acc[i][2] + b4.z;
        r.w = acc[i][3] + b4.w;
        *(float4*)(out + (size_t)m * D_ + n0 + tx * 4) = r;
    }
}

// ---------------------------------------------------------------------------
extern "C" void kernel_launch(void* const* d_in, const int* in_sizes, int n_in,
                              void* d_out, int out_size, void* d_ws, size_t ws_size,
                              hipStream_t stream) {
    const float* x  = (const float*)d_in[0];
    const float* wq = (const float*)d_in[1];
    const float* bq = (const float*)d_in[2];
    const float* wk = (const float*)d_in[3];
    const float* bk = (const float*)d_in[4];
    const float* wv = (const float*)d_in[5];
    const float* bv = (const float*)d_in[6];
    const float* wo = (const float*)d_in[7];
    const float* bo = (const float*)d_in[8];
    float* out = (float*)d_out;

    const size_t BTD = (size_t)B_ * T_ * D_;
    float* q  = (float*)d_ws;                     // [B,H,T,DK]
    float* k  = q + BTD;
    float* v  = k + BTD;
    float* yh = v + BTD;                          // [B,T,D]

    dim3 g1((B_ * T_) / 64, H_, 3);
    qkv_gemm<<<g1, 256, 0, stream>>>(x, wq, bq, wk, bk, wv, bv, q);

    dim3 g2(T_ / QROWS, B_ * H_);                 // 8 x 64 = 512 blocks
    attn<<<g2, 256, 0, stream>>>(q, k, v, yh);

    dim3 g3((B_ * T_) / 64, D_ / 64);
    out_gemm<<<g3, 256, 0, stream>>>(yh, wo, bo, out);
}

// Round 3
// 1150.468 us; speedup vs baseline: 4.6506x; 2.6056x over previous
//
#include <hip/hip_runtime.h>
#include <hip/hip_bf16.h>
#include <cstdint>
#include <cstddef>

#define B_  4
#define T_  2048
#define D_  1024
#define H_  16
#define DK_ 64

typedef __attribute__((ext_vector_type(8))) short bf16x8;   // 8 bf16 = 4 VGPRs (MFMA A/B frag)
typedef __attribute__((ext_vector_type(4))) float f32x4;    // MFMA C/D frag

static __device__ __forceinline__ unsigned short f2bf(float f) {
    __hip_bfloat16 h = __float2bfloat16(f);
    unsigned short u;
    __builtin_memcpy(&u, &h, 2);
    return u;
}

// async global->LDS, 16B per lane, LDS dst = wave-uniform base + lane*16
static __device__ __forceinline__ void gl2lds16(const void* g, void* l) {
    __builtin_amdgcn_global_load_lds(
        (const __attribute__((address_space(1))) unsigned int*)g,
        (__attribute__((address_space(3))) unsigned int*)l,
        16, 0, 0);
}

// ---------------------------------------------------------------------------
// QKV projection (fp32 vector GEMM, 64x64 tile, 4x4 micro-tile).
// NEW epilogue: writes bf16. sel 0/1 -> Q/K natural [bh][t][dk];
// sel 2 -> V transposed [bh][dk][t] (so attention's PV A-frag reads are
// s-contiguous without an in-LDS transpose).
// ---------------------------------------------------------------------------
__global__ __launch_bounds__(256) void qkv_gemm(
    const float* __restrict__ x,
    const float* __restrict__ wq, const float* __restrict__ bq,
    const float* __restrict__ wk, const float* __restrict__ bk,
    const float* __restrict__ wv, const float* __restrict__ bv,
    unsigned short* __restrict__ qkv_out)
{
    const int sel = blockIdx.z;
    const float* w    = (sel == 0) ? wq : (sel == 1) ? wk : wv;
    const float* bias = (sel == 0) ? bq : (sel == 1) ? bk : bv;

    const int m0 = blockIdx.x * 64;
    const int h  = blockIdx.y;
    const int tid = threadIdx.x;
    const int tx = tid & 15;
    const int ty = tid >> 4;

    __shared__ float As[16][68];
    __shared__ float Bs[16][68];

    float acc[4][4];
#pragma unroll
    for (int i = 0; i < 4; ++i)
#pragma unroll
        for (int j = 0; j < 4; ++j) acc[i][j] = 0.f;

    const int lr = tid >> 2;
    const int lc = (tid & 3) * 4;

    const float* aRow = x + (size_t)(m0 + lr) * D_;
    const float* bRow = w + (size_t)(h * 64 + lr) * D_;

    for (int c0 = 0; c0 < D_; c0 += 16) {
        float4 a4 = *(const float4*)(aRow + c0 + lc);
        float4 b4 = *(const float4*)(bRow + c0 + lc);
        __syncthreads();
        As[lc + 0][lr] = a4.x; As[lc + 1][lr] = a4.y;
        As[lc + 2][lr] = a4.z; As[lc + 3][lr] = a4.w;
        Bs[lc + 0][lr] = b4.x; Bs[lc + 1][lr] = b4.y;
        Bs[lc + 2][lr] = b4.z; Bs[lc + 3][lr] = b4.w;
        __syncthreads();
#pragma unroll
        for (int kk = 0; kk < 16; ++kk) {
            float4 av = *(const float4*)&As[kk][ty * 4];
            float4 bv4 = *(const float4*)&Bs[kk][tx * 4];
            float a[4] = {av.x, av.y, av.z, av.w};
            float b[4] = {bv4.x, bv4.y, bv4.z, bv4.w};
#pragma unroll
            for (int i = 0; i < 4; ++i)
#pragma unroll
                for (int j = 0; j < 4; ++j)
                    acc[i][j] += a[i] * b[j];
        }
    }

    const size_t BTD = (size_t)B_ * T_ * D_;
    const int dk0 = tx * 4;
    float4 bb4 = *(const float4*)(bias + h * DK_ + dk0);
    float bb[4] = {bb4.x, bb4.y, bb4.z, bb4.w};

    if (sel < 2) {
        unsigned short* out = qkv_out + (size_t)sel * BTD;
#pragma unroll
        for (int i = 0; i < 4; ++i) {
            const int m = m0 + ty * 4 + i;
            const int b = m >> 11;
            const int t = m & (T_ - 1);
            ushort4 r;
            r.x = f2bf(acc[i][0] + bb[0]);
            r.y = f2bf(acc[i][1] + bb[1]);
            r.z = f2bf(acc[i][2] + bb[2]);
            r.w = f2bf(acc[i][3] + bb[3]);
            *(ushort4*)(out + ((size_t)((b * H_ + h) * T_ + t)) * DK_ + dk0) = r;
        }
    } else {
        unsigned short* out = qkv_out + 2 * BTD;   // vt [bh][dk][t]
        const int b  = m0 >> 11;
        const int t0 = (m0 & (T_ - 1)) + ty * 4;
#pragma unroll
        for (int j = 0; j < 4; ++j) {
            ushort4 r;
            r.x = f2bf(acc[0][j] + bb[j]);
            r.y = f2bf(acc[1][j] + bb[j]);
            r.z = f2bf(acc[2][j] + bb[j]);
            r.w = f2bf(acc[3][j] + bb[j]);
            *(ushort4*)(out + ((size_t)((b * H_ + h) * DK_ + dk0 + j)) * T_ + t0) = r;
        }
    }
}

// ---------------------------------------------------------------------------
// MFMA flash attention. Block = 4 waves x 16 q-rows = 64 q of one (b,h).
// Per 32-key chunk:
//   S^T = K.Q^T via mfma_16x16x32_bf16 (C layout: q = lane&15, s = g*4+reg)
//   softmax row stats local to lane&15 (+2 shfl_xor for the 4 replicas)
//   P -> wave-private LDS round trip into B layout
//   O^T += V^T.P^T via mfma (C layout: q = lane&15, d = g*4+reg)
// K and V^T staged to LDS in fragment-slot order with global_load_lds(16B):
// lane-linear, conflict-free, one instruction per wave per fragment.
// blockIdx.x reversed so heavy (late-t) blocks launch first.
// ---------------------------------------------------------------------------
__global__ __launch_bounds__(256) void attn(
    const unsigned short* __restrict__ qg, const unsigned short* __restrict__ kg,
    const unsigned short* __restrict__ vtg, float* __restrict__ yh)
{
    const int bh  = blockIdx.y;
    const int h   = bh & (H_ - 1);
    const int b   = bh >> 4;
    const int tq0 = ((int)gridDim.x - 1 - (int)blockIdx.x) * 64;
    const int tid  = threadIdx.x;
    const int w    = tid >> 6;
    const int lane = tid & 63;
    const int l15  = lane & 15;
    const int g    = lane >> 4;

    const size_t base = (size_t)bh * T_ * DK_;
    const unsigned short* Qb  = qg  + base;   // [t][dk]
    const unsigned short* Kb  = kg  + base;   // [t][dk]
    const unsigned short* Vtb = vtg + base;   // [dk][t]

    __shared__ __align__(16) unsigned short Kf[4][64 * 8];  // frag f=st*2+kc, slot=lane*8
    __shared__ __align__(16) unsigned short Vf[4][64 * 8];  // frag dt,      slot=lane*8
    __shared__ __align__(16) unsigned short Pb[4][16][40];  // per-wave P buf, stride 40

    const int q0w = tq0 + w * 16;
    const int tq  = q0w + l15;                // the q-row whose stats this lane owns

    // persistent Q B-frags: B[k=dk][n=q]: n=lane&15, k=g*8+i
    bf16x8 qf0 = *(const bf16x8*)(Qb + (size_t)tq * DK_ + g * 8);
    bf16x8 qf1 = *(const bf16x8*)(Qb + (size_t)tq * DK_ + 32 + g * 8);

    f32x4 o0 = {0.f, 0.f, 0.f, 0.f}, o1 = o0, o2 = o0, o3 = o0;
    float mrun = -1e30f, lrun = 0.f;

    // staging addresses for this wave (one K frag + one V^T frag per chunk)
    const int kf_s  = (w >> 1) * 16 + l15;    // K frag: st = w>>1
    const int kf_dk = (w & 1) * 32 + g * 8;   //         kc = w&1
    const int vf_d  = w * 16 + l15;           // V^T frag: dt = w
    const int vf_t  = g * 8;

    const int nCh = (tq0 + 64) / 32;
    for (int ch = 0; ch < nCh; ++ch) {
        const int s0 = ch * 32;
        __syncthreads();                      // previous chunk consumed
        gl2lds16(Kb  + (size_t)(s0 + kf_s) * DK_ + kf_dk, &Kf[w][0]);
        gl2lds16(Vtb + (size_t)vf_d * T_ + s0 + vf_t,     &Vf[w][0]);
        __syncthreads();                      // staged data visible

        if (s0 <= q0w + 15) {                 // wave-uniform causal skip
            float sv[2][4];
#pragma unroll
            for (int st = 0; st < 2; ++st) {
                bf16x8 a0 = *(const bf16x8*)&Kf[st * 2 + 0][lane * 8];
                bf16x8 a1 = *(const bf16x8*)&Kf[st * 2 + 1][lane * 8];
                f32x4 sacc = {0.f, 0.f, 0.f, 0.f};
                sacc = __builtin_amdgcn_mfma_f32_16x16x32_bf16(a0, qf0, sacc, 0, 0, 0);
                sacc = __builtin_amdgcn_mfma_f32_16x16x32_bf16(a1, qf1, sacc, 0, 0, 0);
#pragma unroll
                for (int r = 0; r < 4; ++r) {
                    const int sg = s0 + st * 16 + g * 4 + r;
                    const float v = sacc[r] * 0.125f;     // 1/sqrt(64)
                    sv[st][r] = (sg <= tq) ? v : -3.0e38f;
                }
            }
            // row max over this lane's 8 + the 4 replicas of q
            float mloc = fmaxf(fmaxf(fmaxf(sv[0][0], sv[0][1]), fmaxf(sv[0][2], sv[0][3])),
                               fmaxf(fmaxf(sv[1][0], sv[1][1]), fmaxf(sv[1][2], sv[1][3])));
            mloc = fmaxf(mloc, __shfl_xor(mloc, 16, 64));
            mloc = fmaxf(mloc, __shfl_xor(mloc, 32, 64));
            const float mn    = fmaxf(mrun, mloc);
            const float alpha = __expf(mrun - mn);

            float ps = 0.f;
            ushort4 pk0, pk1;
            {
                float p0 = __expf(sv[0][0] - mn), p1 = __expf(sv[0][1] - mn);
                float p2 = __expf(sv[0][2] - mn), p3 = __expf(sv[0][3] - mn);
                ps += p0 + p1 + p2 + p3;
                pk0.x = f2bf(p0); pk0.y = f2bf(p1); pk0.z = f2bf(p2); pk0.w = f2bf(p3);
                float q0v = __expf(sv[1][0] - mn), q1v = __expf(sv[1][1] - mn);
                float q2v = __expf(sv[1][2] - mn), q3v = __expf(sv[1][3] - mn);
                ps += q0v + q1v + q2v + q3v;
                pk1.x = f2bf(q0v); pk1.y = f2bf(q1v); pk1.z = f2bf(q2v); pk1.w = f2bf(q3v);
            }
            ps += __shfl_xor(ps, 16, 64);
            ps += __shfl_xor(ps, 32, 64);
            lrun = lrun * alpha + ps;
            mrun = mn;

            // P^T -> wave-private LDS (Pb[q][s], s contiguous), then B-frag read
            *(ushort4*)&Pb[w][l15][g * 4]      = pk0;      // s 0..15 tile
            *(ushort4*)&Pb[w][l15][16 + g * 4] = pk1;      // s 16..31 tile
            bf16x8 pf = *(const bf16x8*)&Pb[w][l15][g * 8]; // B[k=s][n=q]

            o0 *= alpha; o1 *= alpha; o2 *= alpha; o3 *= alpha;
            bf16x8 v0 = *(const bf16x8*)&Vf[0][lane * 8];
            bf16x8 v1 = *(const bf16x8*)&Vf[1][lane * 8];
            bf16x8 v2 = *(const bf16x8*)&Vf[2][lane * 8];
            bf16x8 v3 = *(const bf16x8*)&Vf[3][lane * 8];
            o0 = __builtin_amdgcn_mfma_f32_16x16x32_bf16(v0, pf, o0, 0, 0, 0);
            o1 = __builtin_amdgcn_mfma_f32_16x16x32_bf16(v1, pf, o1, 0, 0, 0);
            o2 = __builtin_amdgcn_mfma_f32_16x16x32_bf16(v2, pf, o2, 0, 0, 0);
            o3 = __builtin_amdgcn_mfma_f32_16x16x32_bf16(v3, pf, o3, 0, 0, 0);
        }
    }

    const float inv = 1.f / lrun;
    float* yrow = yh + ((size_t)(b * T_ + tq)) * D_ + h * DK_;
    {
        float4 r;
        r.x = o0[0] * inv; r.y = o0[1] * inv; r.z = o0[2] * inv; r.w = o0[3] * inv;
        *(float4*)(yrow + 0 * 16 + g * 4) = r;
        r.x = o1[0] * inv; r.y = o1[1] * inv; r.z = o1[2] * inv; r.w = o1[3] * inv;
        *(float4*)(yrow + 1 * 16 + g * 4) = r;
        r.x = o2[0] * inv; r.y = o2[1] * inv; r.z = o2[2] * inv; r.w = o2[3] * inv;
        *(float4*)(yrow + 2 * 16 + g * 4) = r;
        r.x = o3[0] * inv; r.y = o3[1] * inv; r.z = o3[2] * inv; r.w = o3[3] * inv;
        *(float4*)(yrow + 3 * 16 + g * 4) = r;
    }
}

// ---------------------------------------------------------------------------
// Output projection: out[m][n] = sum_k yh[m][k] * wo[n][k] + bo[n] (fp32, unchanged)
// ---------------------------------------------------------------------------
__global__ __launch_bounds__(256) void out_gemm(
    const float* __restrict__ yh, const float* __restrict__ wo,
    const float* __restrict__ bo, float* __restrict__ out)
{
    const int m0 = blockIdx.x * 64;
    const int n0 = blockIdx.y * 64;
    const int tid = threadIdx.x;
    const int tx = tid & 15;
    const int ty = tid >> 4;

    __shared__ float As[16][68];
    __shared__ float Bs[16][68];

    float acc[4][4];
#pragma unroll
    for (int i = 0; i < 4; ++i)
#pragma unroll
        for (int j = 0; j < 4; ++j) acc[i][j] = 0.f;

    const int lr = tid >> 2;
    const int lc = (tid & 3) * 4;

    const float* aRow = yh + (size_t)(m0 + lr) * D_;
    const float* bRow = wo + (size_t)(n0 + lr) * D_;

    for (int c0 = 0; c0 < D_; c0 += 16) {
        float4 a4 = *(const float4*)(aRow + c0 + lc);
        float4 b4 = *(const float4*)(bRow + c0 + lc);
        __syncthreads();
        As[lc + 0][lr] = a4.x; As[lc + 1][lr] = a4.y;
        As[lc + 2][lr] = a4.z; As[lc + 3][lr] = a4.w;
        Bs[lc + 0][lr] = b4.x; Bs[lc + 1][lr] = b4.y;
        Bs[lc + 2][lr] = b4.z; Bs[lc + 3][lr] = b4.w;
        __syncthreads();
#pragma unroll
        for (int kk = 0; kk < 16; ++kk) {
            float4 av = *(const float4*)&As[kk][ty * 4];
            float4 bv4 = *(const float4*)&Bs[kk][tx * 4];
            float a[4] = {av.x, av.y, av.z, av.w};
            float b[4] = {bv4.x, bv4.y, bv4.z, bv4.w};
#pragma unroll
            for (int i = 0; i < 4; ++i)
#pragma unroll
                for (int j = 0; j < 4; ++j)
                    acc[i][j] += a[i] * b[j];
        }
    }

    float4 b4 = *(const float4*)(bo + n0 + tx * 4);
#pragma unroll
    for (int i = 0; i < 4; ++i) {
        const int m = m0 + ty * 4 + i;
        float4 r;
        r.x = acc[i][0] + b4.x;
        r.y = acc[i][1] + b4.y;
        r.z = acc[i][2] + b4.z;
        r.w = acc[i][3] + b4.w;
        *(float4*)(out + (size_t)m * D_ + n0 + tx * 4) = r;
    }
}

// ---------------------------------------------------------------------------
extern "C" void kernel_launch(void* const* d_in, const int* in_sizes, int n_in,
                              void* d_out, int out_size, void* d_ws, size_t ws_size,
                              hipStream_t stream) {
    const float* x  = (const float*)d_in[0];
    const float* wq = (const float*)d_in[1];
    const float* bq = (const float*)d_in[2];
    const float* wk = (const float*)d_in[3];
    const float* bk = (const float*)d_in[4];
    const float* wv = (const float*)d_in[5];
    const float* bv = (const float*)d_in[6];
    const float* wo = (const float*)d_in[7];
    const float* bo = (const float*)d_in[8];
    float* out = (float*)d_out;

    const size_t BTD = (size_t)B_ * T_ * D_;          // 8.4M elements
    unsigned short* qkv = (unsigned short*)d_ws;      // q, k, vt bf16: 3*BTD ushorts
    float* yh = (float*)(qkv + 3 * BTD);              // [B,T,D] fp32

    dim3 g1((B_ * T_) / 64, H_, 3);
    qkv_gemm<<<g1, 256, 0, stream>>>(x, wq, bq, wk, bk, wv, bv, qkv);

    dim3 g2(T_ / 64, B_ * H_);                        // 32 x 64 = 2048 blocks
    attn<<<g2, 256, 0, stream>>>(qkv, qkv + BTD, qkv + 2 * BTD, yh);

    dim3 g3((B_ * T_) / 64, D_ / 64);
    out_gemm<<<g3, 256, 0, stream>>>(yh, wo, bo, out);
}

// Round 4
// 414.058 us; speedup vs baseline: 12.9218x; 2.7785x over previous
//
#include <hip/hip_runtime.h>
#include <hip/hip_bf16.h>
#include <cstdint>
#include <cstddef>

#define B_  4
#define T_  2048
#define D_  1024
#define H_  16
#define DK_ 64
#define M_  (B_ * T_)     // 8192 tokens

typedef __attribute__((ext_vector_type(8))) short bf16x8;   // MFMA A/B frag (4 VGPRs)
typedef __attribute__((ext_vector_type(4))) float f32x4;    // MFMA C/D frag

static __device__ __forceinline__ unsigned short f2bf(float f) {
    __hip_bfloat16 h = __float2bfloat16(f);
    unsigned short u;
    __builtin_memcpy(&u, &h, 2);
    return u;
}

// async global->LDS: per-lane 16B global src, LDS dst = wave-uniform base + lane*16
static __device__ __forceinline__ void gl2lds16(const void* g, void* l) {
    __builtin_amdgcn_global_load_lds(
        (const __attribute__((address_space(1))) unsigned int*)g,
        (__attribute__((address_space(3))) unsigned int*)l,
        16, 0, 0);
}

// ---------------------------------------------------------------------------
// fp32 -> bf16 convert: regions [x | wq | wk | wv | wo] -> contiguous dst.
// x = 2097152 vec4, each weight = 262144 (2^18) vec4. Total 3145728 vec4.
// ---------------------------------------------------------------------------
__global__ __launch_bounds__(256) void cvt_bf16(
    const float* __restrict__ x,  const float* __restrict__ wq,
    const float* __restrict__ wk, const float* __restrict__ wv,
    const float* __restrict__ wo, unsigned short* __restrict__ dst)
{
    const int idx = blockIdx.x * 256 + threadIdx.x;   // vec4 index
    const float* src;
    int off;
    if (idx < 2097152) { src = x; off = idx; }
    else {
        const int r = (idx - 2097152) >> 18;
        off = (idx - 2097152) & 262143;
        src = (r == 0) ? wq : (r == 1) ? wk : (r == 2) ? wv : wo;
    }
    float4 v = ((const float4*)src)[off];
    ushort4 o;
    o.x = f2bf(v.x); o.y = f2bf(v.y); o.z = f2bf(v.z); o.w = f2bf(v.w);
    ((ushort4*)dst)[idx] = o;
}

// ---------------------------------------------------------------------------
// QKV MFMA GEMM (m97 structure). A = xb [8192][1024] bf16, B = w [1024][1024]
// bf16 (row-major N x K). 128x128 tile, BK=32, 4 waves, 4x4 16x16 accs/wave.
// LDS fragment-slot staging via global_load_lds(16B). A-frag and B-frag have
// the same lane mapping (16dim = lane&15, k = (lane>>4)*8+j) so staged frags
// serve as either MFMA operand:
//   sel<2 (Q,K): acc = mfma(wfrag, xfrag)  -> D[ch][tok], dk-contig ushort4
//   sel==2 (V):  acc = mfma(xfrag, wfrag)  -> D[tok][ch], t-contig ushort4 (Vt)
// ---------------------------------------------------------------------------
__global__ __launch_bounds__(256) void qkv_gemm(
    const unsigned short* __restrict__ xb,
    const unsigned short* __restrict__ wqb, const unsigned short* __restrict__ wkb,
    const unsigned short* __restrict__ wvb,
    const float* __restrict__ bq, const float* __restrict__ bk,
    const float* __restrict__ bv,
    unsigned short* __restrict__ qkv_out)   // q | k | vt, each M_*D? no: B_*H_*T_*DK_
{
    const int sel = blockIdx.z;
    const unsigned short* wb = (sel == 0) ? wqb : (sel == 1) ? wkb : wvb;
    const float* bias        = (sel == 0) ? bq  : (sel == 1) ? bk  : bv;

    const int m0 = blockIdx.x * 128;        // token tile
    const int n0 = blockIdx.y * 128;        // channel tile
    const int tid = threadIdx.x;
    const int w = tid >> 6, lane = tid & 63;
    const int l15 = lane & 15, g = lane >> 4;

    __shared__ __align__(16) unsigned short Af[8][512];   // x frags
    __shared__ __align__(16) unsigned short Bf[8][512];   // w frags

    f32x4 acc[4][4];
#pragma unroll
    for (int i = 0; i < 4; ++i)
#pragma unroll
        for (int j = 0; j < 4; ++j) acc[i][j] = (f32x4){0.f, 0.f, 0.f, 0.f};

    const int wm = (w & 1) * 4;             // wave's A-subtile base (m)
    const int wn = (w >> 1) * 4;            // wave's B-subtile base (n)

    const unsigned short* aSrc0 = xb + (size_t)(m0 + (w * 2    ) * 16 + l15) * D_ + g * 8;
    const unsigned short* aSrc1 = xb + (size_t)(m0 + (w * 2 + 1) * 16 + l15) * D_ + g * 8;
    const unsigned short* bSrc0 = wb + (size_t)(n0 + (w * 2    ) * 16 + l15) * D_ + g * 8;
    const unsigned short* bSrc1 = wb + (size_t)(n0 + (w * 2 + 1) * 16 + l15) * D_ + g * 8;

    for (int k0 = 0; k0 < D_; k0 += 32) {
        __syncthreads();
        gl2lds16(aSrc0 + k0, &Af[w * 2    ][0]);
        gl2lds16(aSrc1 + k0, &Af[w * 2 + 1][0]);
        gl2lds16(bSrc0 + k0, &Bf[w * 2    ][0]);
        gl2lds16(bSrc1 + k0, &Bf[w * 2 + 1][0]);
        __syncthreads();

        bf16x8 af[4], bf[4];
#pragma unroll
        for (int i = 0; i < 4; ++i) af[i] = *(const bf16x8*)&Af[wm + i][lane * 8];
#pragma unroll
        for (int j = 0; j < 4; ++j) bf[j] = *(const bf16x8*)&Bf[wn + j][lane * 8];

        if (sel < 2) {
#pragma unroll
            for (int i = 0; i < 4; ++i)      // i = channel subtile
#pragma unroll
                for (int j = 0; j < 4; ++j)  // j = token subtile
                    acc[i][j] = __builtin_amdgcn_mfma_f32_16x16x32_bf16(
                        bf[i], af[j], acc[i][j], 0, 0, 0);
        } else {
#pragma unroll
            for (int i = 0; i < 4; ++i)      // i = token subtile
#pragma unroll
                for (int j = 0; j < 4; ++j)  // j = channel subtile
                    acc[i][j] = __builtin_amdgcn_mfma_f32_16x16x32_bf16(
                        af[i], bf[j], acc[i][j], 0, 0, 0);
        }
    }

    const size_t BTD = (size_t)B_ * T_ * D_;
    if (sel < 2) {
        // D[ch][tok]: lane holds ch = base + g*4 + r, tok = base + l15
        unsigned short* out = qkv_out + (size_t)sel * BTD;
#pragma unroll
        for (int i = 0; i < 4; ++i) {
            const int ch0 = n0 + (wn + i) * 16 + g * 4;
            const int h   = ch0 >> 6;
            const int dk0 = ch0 & 63;
            float4 bb = *(const float4*)(bias + ch0);
#pragma unroll
            for (int j = 0; j < 4; ++j) {
                const int tok = m0 + (wm + j) * 16 + l15;
                const int b = tok >> 11, t = tok & (T_ - 1);
                ushort4 r;
                r.x = f2bf(acc[i][j][0] + bb.x);
                r.y = f2bf(acc[i][j][1] + bb.y);
                r.z = f2bf(acc[i][j][2] + bb.z);
                r.w = f2bf(acc[i][j][3] + bb.w);
                *(ushort4*)(out + ((size_t)((b * H_ + h) * T_ + t)) * DK_ + dk0) = r;
            }
        }
    } else {
        // D[tok][ch]: lane holds tok = base + g*4 + r, ch = base + l15 -> Vt[dk][t]
        unsigned short* out = qkv_out + 2 * BTD;
#pragma unroll
        for (int j = 0; j < 4; ++j) {
            const int ch = n0 + (wn + j) * 16 + l15;
            const int h  = ch >> 6;
            const int dk = ch & 63;
            const float bb = bias[ch];
#pragma unroll
            for (int i = 0; i < 4; ++i) {
                const int tok0 = m0 + (wm + i) * 16 + g * 4;
                const int b = tok0 >> 11, t0 = tok0 & (T_ - 1);
                ushort4 r;
                r.x = f2bf(acc[i][j][0] + bb);
                r.y = f2bf(acc[i][j][1] + bb);
                r.z = f2bf(acc[i][j][2] + bb);
                r.w = f2bf(acc[i][j][3] + bb);
                *(ushort4*)(out + ((size_t)((b * H_ + h) * DK_ + dk)) * T_ + t0) = r;
            }
        }
    }
}

// ---------------------------------------------------------------------------
// MFMA flash attention (unchanged R3 structure; yh output now bf16).
// ---------------------------------------------------------------------------
__global__ __launch_bounds__(256) void attn(
    const unsigned short* __restrict__ qg, const unsigned short* __restrict__ kg,
    const unsigned short* __restrict__ vtg, unsigned short* __restrict__ yh)
{
    const int bh  = blockIdx.y;
    const int h   = bh & (H_ - 1);
    const int b   = bh >> 4;
    const int tq0 = ((int)gridDim.x - 1 - (int)blockIdx.x) * 64;
    const int tid  = threadIdx.x;
    const int w    = tid >> 6;
    const int lane = tid & 63;
    const int l15  = lane & 15;
    const int g    = lane >> 4;

    const size_t base = (size_t)bh * T_ * DK_;
    const unsigned short* Qb  = qg  + base;
    const unsigned short* Kb  = kg  + base;
    const unsigned short* Vtb = vtg + base;

    __shared__ __align__(16) unsigned short Kf[4][64 * 8];
    __shared__ __align__(16) unsigned short Vf[4][64 * 8];
    __shared__ __align__(16) unsigned short Pb[4][16][40];

    const int q0w = tq0 + w * 16;
    const int tq  = q0w + l15;

    bf16x8 qf0 = *(const bf16x8*)(Qb + (size_t)tq * DK_ + g * 8);
    bf16x8 qf1 = *(const bf16x8*)(Qb + (size_t)tq * DK_ + 32 + g * 8);

    f32x4 o0 = {0.f, 0.f, 0.f, 0.f}, o1 = o0, o2 = o0, o3 = o0;
    float mrun = -1e30f, lrun = 0.f;

    const int kf_s  = (w >> 1) * 16 + l15;
    const int kf_dk = (w & 1) * 32 + g * 8;
    const int vf_d  = w * 16 + l15;
    const int vf_t  = g * 8;

    const int nCh = (tq0 + 64) / 32;
    for (int ch = 0; ch < nCh; ++ch) {
        const int s0 = ch * 32;
        __syncthreads();
        gl2lds16(Kb  + (size_t)(s0 + kf_s) * DK_ + kf_dk, &Kf[w][0]);
        gl2lds16(Vtb + (size_t)vf_d * T_ + s0 + vf_t,     &Vf[w][0]);
        __syncthreads();

        if (s0 <= q0w + 15) {
            float sv[2][4];
#pragma unroll
            for (int st = 0; st < 2; ++st) {
                bf16x8 a0 = *(const bf16x8*)&Kf[st * 2 + 0][lane * 8];
                bf16x8 a1 = *(const bf16x8*)&Kf[st * 2 + 1][lane * 8];
                f32x4 sacc = {0.f, 0.f, 0.f, 0.f};
                sacc = __builtin_amdgcn_mfma_f32_16x16x32_bf16(a0, qf0, sacc, 0, 0, 0);
                sacc = __builtin_amdgcn_mfma_f32_16x16x32_bf16(a1, qf1, sacc, 0, 0, 0);
#pragma unroll
                for (int r = 0; r < 4; ++r) {
                    const int sg = s0 + st * 16 + g * 4 + r;
                    const float v = sacc[r] * 0.125f;
                    sv[st][r] = (sg <= tq) ? v : -3.0e38f;
                }
            }
            float mloc = fmaxf(fmaxf(fmaxf(sv[0][0], sv[0][1]), fmaxf(sv[0][2], sv[0][3])),
                               fmaxf(fmaxf(sv[1][0], sv[1][1]), fmaxf(sv[1][2], sv[1][3])));
            mloc = fmaxf(mloc, __shfl_xor(mloc, 16, 64));
            mloc = fmaxf(mloc, __shfl_xor(mloc, 32, 64));
            const float mn    = fmaxf(mrun, mloc);
            const float alpha = __expf(mrun - mn);

            float ps = 0.f;
            ushort4 pk0, pk1;
            {
                float p0 = __expf(sv[0][0] - mn), p1 = __expf(sv[0][1] - mn);
                float p2 = __expf(sv[0][2] - mn), p3 = __expf(sv[0][3] - mn);
                ps += p0 + p1 + p2 + p3;
                pk0.x = f2bf(p0); pk0.y = f2bf(p1); pk0.z = f2bf(p2); pk0.w = f2bf(p3);
                float q0v = __expf(sv[1][0] - mn), q1v = __expf(sv[1][1] - mn);
                float q2v = __expf(sv[1][2] - mn), q3v = __expf(sv[1][3] - mn);
                ps += q0v + q1v + q2v + q3v;
                pk1.x = f2bf(q0v); pk1.y = f2bf(q1v); pk1.z = f2bf(q2v); pk1.w = f2bf(q3v);
            }
            ps += __shfl_xor(ps, 16, 64);
            ps += __shfl_xor(ps, 32, 64);
            lrun = lrun * alpha + ps;
            mrun = mn;

            *(ushort4*)&Pb[w][l15][g * 4]      = pk0;
            *(ushort4*)&Pb[w][l15][16 + g * 4] = pk1;
            bf16x8 pf = *(const bf16x8*)&Pb[w][l15][g * 8];

            o0 *= alpha; o1 *= alpha; o2 *= alpha; o3 *= alpha;
            bf16x8 v0 = *(const bf16x8*)&Vf[0][lane * 8];
            bf16x8 v1 = *(const bf16x8*)&Vf[1][lane * 8];
            bf16x8 v2 = *(const bf16x8*)&Vf[2][lane * 8];
            bf16x8 v3 = *(const bf16x8*)&Vf[3][lane * 8];
            o0 = __builtin_amdgcn_mfma_f32_16x16x32_bf16(v0, pf, o0, 0, 0, 0);
            o1 = __builtin_amdgcn_mfma_f32_16x16x32_bf16(v1, pf, o1, 0, 0, 0);
            o2 = __builtin_amdgcn_mfma_f32_16x16x32_bf16(v2, pf, o2, 0, 0, 0);
            o3 = __builtin_amdgcn_mfma_f32_16x16x32_bf16(v3, pf, o3, 0, 0, 0);
        }
    }

    const float inv = 1.f / lrun;
    unsigned short* yrow = yh + ((size_t)(b * T_ + tq)) * D_ + h * DK_;
    {
        ushort4 r;
        r.x = f2bf(o0[0] * inv); r.y = f2bf(o0[1] * inv);
        r.z = f2bf(o0[2] * inv); r.w = f2bf(o0[3] * inv);
        *(ushort4*)(yrow + 0 * 16 + g * 4) = r;
        r.x = f2bf(o1[0] * inv); r.y = f2bf(o1[1] * inv);
        r.z = f2bf(o1[2] * inv); r.w = f2bf(o1[3] * inv);
        *(ushort4*)(yrow + 1 * 16 + g * 4) = r;
        r.x = f2bf(o2[0] * inv); r.y = f2bf(o2[1] * inv);
        r.z = f2bf(o2[2] * inv); r.w = f2bf(o2[3] * inv);
        *(ushort4*)(yrow + 2 * 16 + g * 4) = r;
        r.x = f2bf(o3[0] * inv); r.y = f2bf(o3[1] * inv);
        r.z = f2bf(o3[2] * inv); r.w = f2bf(o3[3] * inv);
        *(ushort4*)(yrow + 3 * 16 + g * 4) = r;
    }
}

// ---------------------------------------------------------------------------
// Output MFMA GEMM: out[tok][ch] fp32 = yhb . wob^T + bo.
// Orientation D[ch][tok] (mfma(wofrag, yhfrag)) -> ch-contiguous float4 store.
// ---------------------------------------------------------------------------
__global__ __launch_bounds__(256) void out_gemm(
    const unsigned short* __restrict__ yhb, const unsigned short* __restrict__ wob,
    const float* __restrict__ bo, float* __restrict__ out)
{
    const int m0 = blockIdx.x * 128;
    const int n0 = blockIdx.y * 128;
    const int tid = threadIdx.x;
    const int w = tid >> 6, lane = tid & 63;
    const int l15 = lane & 15, g = lane >> 4;

    __shared__ __align__(16) unsigned short Af[8][512];
    __shared__ __align__(16) unsigned short Bf[8][512];

    f32x4 acc[4][4];
#pragma unroll
    for (int i = 0; i < 4; ++i)
#pragma unroll
        for (int j = 0; j < 4; ++j) acc[i][j] = (f32x4){0.f, 0.f, 0.f, 0.f};

    const int wm = (w & 1) * 4;
    const int wn = (w >> 1) * 4;

    const unsigned short* aSrc0 = yhb + (size_t)(m0 + (w * 2    ) * 16 + l15) * D_ + g * 8;
    const unsigned short* aSrc1 = yhb + (size_t)(m0 + (w * 2 + 1) * 16 + l15) * D_ + g * 8;
    const unsigned short* bSrc0 = wob + (size_t)(n0 + (w * 2    ) * 16 + l15) * D_ + g * 8;
    const unsigned short* bSrc1 = wob + (size_t)(n0 + (w * 2 + 1) * 16 + l15) * D_ + g * 8;

    for (int k0 = 0; k0 < D_; k0 += 32) {
        __syncthreads();
        gl2lds16(aSrc0 + k0, &Af[w * 2    ][0]);
        gl2lds16(aSrc1 + k0, &Af[w * 2 + 1][0]);
        gl2lds16(bSrc0 + k0, &Bf[w * 2    ][0]);
        gl2lds16(bSrc1 + k0, &Bf[w * 2 + 1][0]);
        __syncthreads();

        bf16x8 af[4], bf[4];
#pragma unroll
        for (int i = 0; i < 4; ++i) af[i] = *(const bf16x8*)&Af[wm + i][lane * 8];
#pragma unroll
        for (int j = 0; j < 4; ++j) bf[j] = *(const bf16x8*)&Bf[wn + j][lane * 8];

#pragma unroll
        for (int i = 0; i < 4; ++i)          // i = channel subtile
#pragma unroll
            for (int j = 0; j < 4; ++j)      // j = token subtile
                acc[i][j] = __builtin_amdgcn_mfma_f32_16x16x32_bf16(
                    bf[i], af[j], acc[i][j], 0, 0, 0);
    }

#pragma unroll
    for (int i = 0; i < 4; ++i) {
        const int ch0 = n0 + (wn + i) * 16 + g * 4;
        float4 bb = *(const float4*)(bo + ch0);
#pragma unroll
        for (int j = 0; j < 4; ++j) {
            const int tok = m0 + (wm + j) * 16 + l15;
            float4 r;
            r.x = acc[i][j][0] + bb.x;
            r.y = acc[i][j][1] + bb.y;
            r.z = acc[i][j][2] + bb.z;
            r.w = acc[i][j][3] + bb.w;
            *(float4*)(out + (size_t)tok * D_ + ch0) = r;
        }
    }
}

// ---------------------------------------------------------------------------
extern "C" void kernel_launch(void* const* d_in, const int* in_sizes, int n_in,
                              void* d_out, int out_size, void* d_ws, size_t ws_size,
                              hipStream_t stream) {
    const float* x  = (const float*)d_in[0];
    const float* wq = (const float*)d_in[1];
    const float* bq = (const float*)d_in[2];
    const float* wk = (const float*)d_in[3];
    const float* bk = (const float*)d_in[4];
    const float* wv = (const float*)d_in[5];
    const float* bv = (const float*)d_in[6];
    const float* wo = (const float*)d_in[7];
    const float* bo = (const float*)d_in[8];
    float* out = (float*)d_out;

    const size_t BTD = (size_t)B_ * T_ * D_;          // 8388608
    const size_t WSZ = (size_t)D_ * D_;               // 1048576
    unsigned short* xb  = (unsigned short*)d_ws;      // bf16 regions, contiguous:
    unsigned short* wqb = xb  + BTD;                  // [x | wq | wk | wv | wo]
    unsigned short* wkb = wqb + WSZ;
    unsigned short* wvb = wkb + WSZ;
    unsigned short* wob = wvb + WSZ;
    unsigned short* qb  = wob + WSZ;                  // q | k | vt bf16
    unsigned short* kb  = qb  + BTD;
    unsigned short* vtb = kb  + BTD;
    unsigned short* yhb = vtb + BTD;                  // yh bf16 [B,T,D]
    // total ws: (1 + 3 + 1) * 16.78 MB + 4 * 2 MB = ~92 MB

    // 0. fp32 -> bf16 conversions (x + 4 weight matrices)
    cvt_bf16<<<dim3(12288), 256, 0, stream>>>(x, wq, wk, wv, wo, xb);

    // 1. QKV projections (bf16 MFMA)
    dim3 g1(M_ / 128, D_ / 128, 3);
    qkv_gemm<<<g1, 256, 0, stream>>>(xb, wqb, wkb, wvb, bq, bk, bv, qb);

    // 2. causal MFMA flash attention
    dim3 g2(T_ / 64, B_ * H_);
    attn<<<g2, 256, 0, stream>>>(qb, kb, vtb, yhb);

    // 3. output projection (bf16 MFMA, fp32 out)
    dim3 g3(M_ / 128, D_ / 128);
    out_gemm<<<g3, 256, 0, stream>>>(yhb, wob, bo, out);
}